// Round 13
// baseline (512.559 us; speedup 1.0000x reference)
//
#include <hip/hip_runtime.h>
#include <hip/hip_bf16.h>

// Problem constants
#define NN   20000          // nodes
#define DIN_ 92             // atom feature dim
#define CC   128            // hidden dim
#define EE   640000         // edges (self loops handled explicitly)
#define CAP  128            // adjacency bucket capacity (deg ~ Poisson(32); P(>128) ~ 0)
#define BN_EPS 1e-5f

typedef short short8 __attribute__((ext_vector_type(8)));
typedef float floatx4 __attribute__((ext_vector_type(4)));

// ---------------------------------------------------------------------------
// Dual-dtype helpers: flags[0]=1 -> external floats are fp32 (else bf16)
//                     flags[1]=1 -> edge_index is int64 (else int32)
// ---------------------------------------------------------------------------
static __device__ __forceinline__ float b2f(__hip_bfloat16 v) { return __bfloat162float(v); }
static __device__ __forceinline__ float ldf(const void* p, int i, int f32) {
    return f32 ? ((const float*)p)[i]
               : __bfloat162float(((const __hip_bfloat16*)p)[i]);
}
static __device__ __forceinline__ void stf(void* p, int i, float v, int f32) {
    if (f32) ((float*)p)[i] = v;
    else     ((__hip_bfloat16*)p)[i] = __float2bfloat16(v);
}
static __device__ __forceinline__ float leaky02(float x) { return x > 0.f ? x : 0.2f * x; }

// bf16 decode via bit ops (bf16 = top half of fp32)
static __device__ __forceinline__ float2 bfp(unsigned w) {
    return make_float2(__uint_as_float(w << 16), __uint_as_float(w & 0xffff0000u));
}
static __device__ __forceinline__ float4 bf4(unsigned x, unsigned y) {
    return make_float4(__uint_as_float(x << 16), __uint_as_float(x & 0xffff0000u),
                       __uint_as_float(y << 16), __uint_as_float(y & 0xffff0000u));
}
static __device__ __forceinline__ uint2 f4bf(float4 v) {
    union { uint2 u; __hip_bfloat16 b[4]; } x;
    x.b[0] = __float2bfloat16(v.x); x.b[1] = __float2bfloat16(v.y);
    x.b[2] = __float2bfloat16(v.z); x.b[3] = __float2bfloat16(v.w);
    return x.u;
}
static __device__ __forceinline__ unsigned f2bf(float2 v) {
    union { unsigned u; __hip_bfloat16 b[2]; } x;
    x.b[0] = __float2bfloat16(v.x); x.b[1] = __float2bfloat16(v.y);
    return x.u;
}
static __device__ __forceinline__ short bf16s(float v) {
    union { __hip_bfloat16 b; unsigned short u; } cv;
    cv.b = __float2bfloat16(v);
    return (short)cv.u;
}

// ---------------------------------------------------------------------------
// Merged conversion + region-partitioned bucket scatter (block-role split).
// Blocks [0, HB): scatter role — edges whose dst region (d/2500) matches
//   blockIdx&7 -> csr16[d*CAP + atomicAdd(&deg[d],1)] = s. Region
//   partitioning keeps bucket writes XCD-local (r10: global version had
//   ~8x HBM write amplification from non-coherent per-XCD L2s).
// Blocks [HB, HB+CVTB): conversion role; first cvt block publishes FLAGS.
// DEG/SUMSALL zeroed by a memset BEFORE this kernel.
// ---------------------------------------------------------------------------
#define R0_ 12288
#define R1_ (R0_ + 16384)
#define R2_ (R1_ + 16384)
#define R3_ (R2_ + 16384)
#define R4_ (R3_ + 16384)
#define R5_ (R4_ + 32768)
#define R6_ (R5_ + 32768)          // 143360 weight elements
#define TCVT (R6_ + NN * 96)       // + node features
#define CHUNK 2048
#define NCH ((EE + CHUNK - 1) / CHUNK)   // 313 chunks
#define HB (NCH * 8)               // 2504 scatter blocks
#define CVTB ((TCVT + 255) / 256)  // cvt blocks

__global__ __launch_bounds__(256) void cvt_scatter_kernel(
    const void* __restrict__ w_emb, const void* __restrict__ w1,
    const void* __restrict__ w2, const void* __restrict__ wmu,
    const void* __restrict__ wvar, const void* __restrict__ wgat,
    const void* __restrict__ wdec, const void* __restrict__ xin,
    const unsigned* __restrict__ ei,
    __hip_bfloat16* __restrict__ dst,
    int* __restrict__ flags, int* __restrict__ deg,
    unsigned short* __restrict__ csr)
{
    if ((int)blockIdx.x < HB) {
        // -------- scatter role --------
        __shared__ int cz;
        if (threadIdx.x == 0) cz = 0;
        __syncthreads();
        if (ei[2 * threadIdx.x + 1] == 0u) atomicAdd(&cz, 1);
        __syncthreads();
        const int i64 = (cz >= 250);
        int r = blockIdx.x & 7;
        int c = blockIdx.x >> 3;
        int base = c * CHUNK + threadIdx.x;
#pragma unroll
        for (int k = 0; k < CHUNK / 256; k++) {
            int e = base + k * 256;
            if (e < EE) {
                int d = i64 ? (int)((const long long*)ei)[EE + e] : ((const int*)ei)[EE + e];
                if (d / 2500 == r) {
                    int s = i64 ? (int)((const long long*)ei)[e] : ((const int*)ei)[e];
                    int pos = atomicAdd(&deg[d], 1);
                    if (pos < CAP) csr[(d << 7) + pos] = (unsigned short)s;
                }
            }
        }
        return;
    }

    // -------- conversion role --------
    __shared__ int cnt_band, cnt_zero;
    if (threadIdx.x == 0) { cnt_band = 0; cnt_zero = 0; }
    __syncthreads();
    {
        unsigned wv = ((const unsigned*)xin)[threadIdx.x];
        unsigned eb = ((wv & 0xFFFFu) >> 7) & 0xFFu;
        if (eb >= 90u && eb <= 140u) atomicAdd(&cnt_band, 1);
        if ((int)blockIdx.x == HB && ei[2 * threadIdx.x + 1] == 0u) atomicAdd(&cnt_zero, 1);
    }
    __syncthreads();
    const int f32 = (cnt_band < 200) ? 1 : 0;
    if ((int)blockIdx.x == HB && threadIdx.x == 0) {
        flags[0] = f32;
        flags[1] = (cnt_zero >= 250) ? 1 : 0;
    }

    int i = ((int)blockIdx.x - HB) * 256 + threadIdx.x;
    if (i >= TCVT) return;
    float v;
    if (i < R0_) {
        int n = i / 96, k = i - n * 96;
        v = (k < DIN_) ? ldf(w_emb, k * 128 + n, f32) : 0.f;
    } else if (i < R1_) {
        int j = i - R0_; int n = j >> 7, k = j & 127; v = ldf(w1, k * 128 + n, f32);
    } else if (i < R2_) {
        int j = i - R1_; int n = j >> 7, k = j & 127; v = ldf(w2, k * 128 + n, f32);
    } else if (i < R3_) {
        int j = i - R2_; int n = j >> 7, k = j & 127; v = ldf(wmu, k * 128 + n, f32);
    } else if (i < R4_) {
        int j = i - R3_; int n = j >> 7, k = j & 127; v = ldf(wvar, k * 128 + n, f32);
    } else if (i < R5_) {
        int j = i - R4_; int n = j >> 7, k = j & 127; v = ldf(wgat, k * 256 + n, f32);
    } else if (i < R6_) {
        int j = i - R5_; int n = j >> 8, k = j & 255; v = ldf(wdec, k * 128 + n, f32);
    } else {
        int j = i - R6_; int row = j / 96, k = j - row * 96;
        v = (k < DIN_) ? ldf(xin, row * DIN_ + k, f32) : 0.f;
    }
    dst[i] = __float2bfloat16(v);
}

// ---------------------------------------------------------------------------
// MFMA GEMM (16x16x32 bf16): C[M,NC] = A @ W + bias.
// STATS=1: per-column sum/sumsq quad-reduced via shfl_xor, written as
//   NON-ATOMIC per-block partials (r11: direct atomicAdd = 1250 serialized
//   device-atomics per address ~ 44 us tail; partials + reduce ~40x cheaper).
// BN_A=1 : fused BN+ReLU on the A-load path.
// ---------------------------------------------------------------------------
template<int KP, int NC, int CG, int OUT_MODE, int STATS, int BN_A>
__global__ __launch_bounds__(256) void mfma_gemm_kernel(
    const __hip_bfloat16* __restrict__ A,
    const __hip_bfloat16* __restrict__ WT,
    const void* __restrict__ bias,
    void* __restrict__ Cout, int out_off, float* __restrict__ part,
    const float* __restrict__ bnsums, const void* __restrict__ bng,
    const void* __restrict__ bnbe, const int* __restrict__ flags)
{
    const int f32 = flags[0];
    constexpr int MB = 16 * (4 / CG);
    constexpr int CT = NC / (16 * CG);
    __shared__ float sc_s[128], sh_s[128];
    if (BN_A) {
        int t = threadIdx.x;
        if (t < 128) {
            float mean = bnsums[t] * (1.f / NN);
            float var  = bnsums[128 + t] * (1.f / NN) - mean * mean;
            float rs   = rsqrtf(fmaxf(var, 0.f) + BN_EPS);
            float g    = ldf(bng, t, f32);
            float sc   = rs * g;
            sc_s[t] = sc;
            sh_s[t] = ldf(bnbe, t, f32) - mean * sc;
        }
        __syncthreads();
    }
    int w = threadIdx.x >> 6, l = threadIdx.x & 63;
    int rt = w / CG, cg = w - rt * CG;
    int m0 = blockIdx.x * MB + rt * 16;
    int n0 = cg * (16 * CT);
    int l15 = l & 15, kq = (l >> 4) * 8;
    const __hip_bfloat16* arow = A + (size_t)(m0 + l15) * KP + kq;

    floatx4 acc[CT];
#pragma unroll
    for (int ct = 0; ct < CT; ct++) acc[ct] = (floatx4){0.f, 0.f, 0.f, 0.f};

    for (int kc = 0; kc < KP / 32; kc++) {
        short8 a = *(const short8*)(arow + kc * 32);
        if (BN_A) {
#pragma unroll
            for (int k = 0; k < 8; k++) {
                int c = kq + kc * 32 + k;
                float v = __uint_as_float(((unsigned)(unsigned short)a[k]) << 16);
                float o = v * sc_s[c] + sh_s[c];
                a[k] = bf16s(o > 0.f ? o : 0.f);
            }
        }
#pragma unroll
        for (int ct = 0; ct < CT; ct++) {
            const __hip_bfloat16* brow = WT + (size_t)(n0 + ct * 16 + l15) * KP + kq;
            short8 b = *(const short8*)(brow + kc * 32);
            acc[ct] = __builtin_amdgcn_mfma_f32_16x16x32_bf16(a, b, acc[ct], 0, 0, 0);
        }
    }

    int quad = l >> 4;
#pragma unroll
    for (int ct = 0; ct < CT; ct++) {
        int col = n0 + ct * 16 + l15;
        float bb = bias ? ldf(bias, col, f32) : 0.f;
        float sl = 0.f, ql = 0.f;
#pragma unroll
        for (int r = 0; r < 4; r++) {
            int row = m0 + quad * 4 + r;
            float v = acc[ct][r] + bb;
            size_t o = (size_t)row * NC + col;
            if (OUT_MODE == 0)      ((float*)Cout)[o] = v;
            else if (OUT_MODE == 1) ((__hip_bfloat16*)Cout)[o] = __float2bfloat16(v);
            else                    stf(Cout, out_off + (int)o, v, f32);
            if (STATS) { sl += v; ql += v * v; }
        }
        if (STATS) {
            sl += __shfl_xor(sl, 16); sl += __shfl_xor(sl, 32);
            ql += __shfl_xor(ql, 16); ql += __shfl_xor(ql, 32);
            if (quad == 0) {
                part[blockIdx.x * 512 + rt * 256 + col] = sl;
                part[blockIdx.x * 512 + rt * 256 + 128 + col] = ql;
            }
        }
    }
}

// ---------------------------------------------------------------------------
// Fused GIN gather + W1 GEMM (row-aligned dependency, like zatt/decatt):
// 16-row blocks (1250). Phase 1: 8 half-waves gather 2 dsts each —
// H[d] = X[d] + sum X[s] (BN+ReLU inline if BN_A) — into LDS ab[16][136]
// (pad 136 breaks the 16-way stride-256B bank conflict). Phase 2: MFMA
// with A from LDS (CG=4 geometry: wave w covers cols w*32, CT=2).
// Eliminates the Hbf round-trip (2x10 MB) + the gather dispatch per layer.
// STATS partials: sum->blk*512+col, sumsq->blk*512+128+col; the rt=1 half
// (+256,+384) is zero-filled so bn_reduce's two-half layout stays valid.
// ---------------------------------------------------------------------------
template<int BN_A>
__global__ __launch_bounds__(256) void gemm_gin_kernel(
    const uint2* __restrict__ X2, const __hip_bfloat16* __restrict__ WT,
    const void* __restrict__ bias, __hip_bfloat16* __restrict__ Cout,
    float* __restrict__ part,
    const int* __restrict__ deg, const unsigned short* __restrict__ csr,
    const float* __restrict__ bnsums, const void* __restrict__ bng,
    const void* __restrict__ bnbe, const int* __restrict__ flags)
{
    const int f32 = flags[0];
    __shared__ __hip_bfloat16 ab[16][136];
    __shared__ float sc_s[128], sh_s[128];
    int t = threadIdx.x;
    if (BN_A) {
        if (t < 128) {
            float mean = bnsums[t] * (1.f / NN);
            float var  = bnsums[128 + t] * (1.f / NN) - mean * mean;
            float rs   = rsqrtf(fmaxf(var, 0.f) + BN_EPS);
            float g    = ldf(bng, t, f32);
            float sc   = rs * g;
            sc_s[t] = sc;
            sh_s[t] = ldf(bnbe, t, f32) - mean * sc;
        }
        __syncthreads();
    }
    int m0 = blockIdx.x * 16;

    // ---- phase 1: gather (8 half-waves x 2 dsts) ----
    int hwl = t >> 5;            // 0..7
    int l5  = t & 31;
    int c4  = 4 * l5;
    float sc0 = 0.f, sc1 = 0.f, sc2 = 0.f, sc3 = 0.f;
    float sh0 = 0.f, sh1 = 0.f, sh2 = 0.f, sh3 = 0.f;
    if (BN_A) {
        sc0 = sc_s[c4 + 0]; sc1 = sc_s[c4 + 1]; sc2 = sc_s[c4 + 2]; sc3 = sc_s[c4 + 3];
        sh0 = sh_s[c4 + 0]; sh1 = sh_s[c4 + 1]; sh2 = sh_s[c4 + 2]; sh3 = sh_s[c4 + 3];
    }
#define GBNR(f) do { if (BN_A) { \
    f.x = fmaxf(f.x * sc0 + sh0, 0.f); \
    f.y = fmaxf(f.y * sc1 + sh1, 0.f); \
    f.z = fmaxf(f.z * sc2 + sh2, 0.f); \
    f.w = fmaxf(f.w * sc3 + sh3, 0.f); } } while (0)
#pragma unroll
    for (int q = 0; q < 2; q++) {
        int row = hwl * 2 + q;
        int d = m0 + row;
        uint2 w0 = X2[(size_t)d * 32 + l5];
        float4 acc = bf4(w0.x, w0.y);
        GBNR(acc);
        int b = d << 7;
        int e = b + min(deg[d], CAP);
        int i = b;
        for (; i + 4 <= e; i += 4) {
            int s0 = csr[i], s1 = csr[i + 1], s2 = csr[i + 2], s3 = csr[i + 3];
            uint2 a0 = X2[(size_t)s0 * 32 + l5];
            uint2 a1 = X2[(size_t)s1 * 32 + l5];
            uint2 a2 = X2[(size_t)s2 * 32 + l5];
            uint2 a3 = X2[(size_t)s3 * 32 + l5];
            float4 f0 = bf4(a0.x, a0.y), f1 = bf4(a1.x, a1.y);
            float4 f2 = bf4(a2.x, a2.y), f3 = bf4(a3.x, a3.y);
            GBNR(f0); GBNR(f1); GBNR(f2); GBNR(f3);
            acc.x += f0.x + f1.x + f2.x + f3.x;
            acc.y += f0.y + f1.y + f2.y + f3.y;
            acc.z += f0.z + f1.z + f2.z + f3.z;
            acc.w += f0.w + f1.w + f2.w + f3.w;
        }
        for (; i < e; i++) {
            uint2 a = X2[(size_t)csr[i] * 32 + l5];
            float4 f = bf4(a.x, a.y);
            GBNR(f);
            acc.x += f.x; acc.y += f.y; acc.z += f.z; acc.w += f.w;
        }
        ab[row][c4 + 0] = __float2bfloat16(acc.x);
        ab[row][c4 + 1] = __float2bfloat16(acc.y);
        ab[row][c4 + 2] = __float2bfloat16(acc.z);
        ab[row][c4 + 3] = __float2bfloat16(acc.w);
    }
#undef GBNR
    __syncthreads();

    // ---- phase 2: MFMA (16 rows, CG=4: wave w covers cols w*32, CT=2) ----
    int w = t >> 6, l = t & 63;
    int n0 = w * 32;
    int l15 = l & 15, quad = l >> 4, kq = quad * 8;
    floatx4 acc[2];
    acc[0] = (floatx4){0.f, 0.f, 0.f, 0.f};
    acc[1] = (floatx4){0.f, 0.f, 0.f, 0.f};
    for (int kc = 0; kc < 4; kc++) {
        short8 a = *(const short8*)(&ab[l15][kq + kc * 32]);
#pragma unroll
        for (int ct = 0; ct < 2; ct++) {
            const __hip_bfloat16* brow = WT + (size_t)(n0 + ct * 16 + l15) * 128 + kq;
            short8 b = *(const short8*)(brow + kc * 32);
            acc[ct] = __builtin_amdgcn_mfma_f32_16x16x32_bf16(a, b, acc[ct], 0, 0, 0);
        }
    }
#pragma unroll
    for (int ct = 0; ct < 2; ct++) {
        int col = n0 + ct * 16 + l15;
        float bb = ldf(bias, col, f32);
        float sl = 0.f, ql = 0.f;
#pragma unroll
        for (int r = 0; r < 4; r++) {
            int row = m0 + quad * 4 + r;
            float v = acc[ct][r] + bb;
            Cout[(size_t)row * 128 + col] = __float2bfloat16(v);
            sl += v; ql += v * v;
        }
        sl += __shfl_xor(sl, 16); sl += __shfl_xor(sl, 32);
        ql += __shfl_xor(ql, 16); ql += __shfl_xor(ql, 32);
        if (quad == 0) {
            part[blockIdx.x * 512 + col] = sl;
            part[blockIdx.x * 512 + 128 + col] = ql;
            part[blockIdx.x * 512 + 256 + col] = 0.f;
            part[blockIdx.x * 512 + 384 + col] = 0.f;
        }
    }
}

// ---------------------------------------------------------------------------
// Reduce GEMM per-block BN partials -> sums[256] (sum | sumsq).
// 8 blocks x 256 threads; 8 atomics per address total — negligible.
// ---------------------------------------------------------------------------
__global__ void bn_reduce_kernel(const float* __restrict__ part, float* __restrict__ sums,
                                 int nblk)
{
    int c = threadIdx.x;
    int per = (nblk + (int)gridDim.x - 1) / (int)gridDim.x;
    int b0 = blockIdx.x * per;
    int b1 = min(b0 + per, nblk);
    float v = 0.f;
    for (int b = b0; b < b1; b++)
        v += part[b * 512 + c] + part[b * 512 + 256 + c];
    atomicAdd(&sums[c], v);
}

// ---------------------------------------------------------------------------
// Fused VAE-head GEMM + reparameterization + GAT GEMM + attention scores.
// ---------------------------------------------------------------------------
__global__ __launch_bounds__(256) void gemm_zatt_kernel(
    const __hip_bfloat16* __restrict__ A, const __hip_bfloat16* __restrict__ WTmuv,
    const __hip_bfloat16* __restrict__ WTgat,
    const void* __restrict__ eps, const void* __restrict__ b_mu, const void* __restrict__ b_var,
    __hip_bfloat16* __restrict__ HH,
    const void* __restrict__ attS, const void* __restrict__ attD,
    float* __restrict__ AS, float* __restrict__ AD,
    void* __restrict__ out, const int* __restrict__ flags)
{
    const int f32 = flags[0];
    __shared__ float zs[16][257];
    __shared__ __hip_bfloat16 zb[16][136];
    __shared__ float sS[4][16], sD[4][16];
    int w = threadIdx.x >> 6, l = threadIdx.x & 63;
    int m0 = blockIdx.x * 16;
    int n0 = w * 64;
    int l15 = l & 15, quad = l >> 4, kq = quad * 8;
    const __hip_bfloat16* arow = A + (size_t)(m0 + l15) * 128 + kq;

    // -------- phase 1: mu|logvar GEMM --------
    floatx4 acc[4];
#pragma unroll
    for (int ct = 0; ct < 4; ct++) acc[ct] = (floatx4){0.f, 0.f, 0.f, 0.f};
    for (int kc = 0; kc < 4; kc++) {
        short8 a = *(const short8*)(arow + kc * 32);
#pragma unroll
        for (int ct = 0; ct < 4; ct++) {
            const __hip_bfloat16* brow = WTmuv + (size_t)(n0 + ct * 16 + l15) * 128 + kq;
            short8 b = *(const short8*)(brow + kc * 32);
            acc[ct] = __builtin_amdgcn_mfma_f32_16x16x32_bf16(a, b, acc[ct], 0, 0, 0);
        }
    }
#pragma unroll
    for (int ct = 0; ct < 4; ct++) {
#pragma unroll
        for (int r = 0; r < 4; r++)
            zs[quad * 4 + r][n0 + ct * 16 + l15] = acc[ct][r];
    }
    __syncthreads();
    int t = threadIdx.x;
    const int NB2 = NN * CC;
#pragma unroll
    for (int k = 0; k < 8; k++) {
        int idx = k * 256 + t;
        int row = idx >> 7, c = idx & 127;
        float mu = zs[row][c]       + ldf(b_mu,  c, f32);
        float lv = zs[row][128 + c] + ldf(b_var, c, f32);
        int gi = (m0 + row) * 128 + c;
        float z = ldf(eps, gi, f32) * expf(0.5f * lv) + mu;
        zb[row][c] = __float2bfloat16(z);
        stf(out, gi, z, f32);                 // zin
        stf(out, 2 * NB2 + gi, mu, f32);      // mu
        stf(out, 3 * NB2 + gi, lv, f32);      // logvar
    }
    __syncthreads();

    // -------- phase 2: GAT GEMM + attention epilogue --------
    int h = w >> 1;
    floatx4 acc2[4];
#pragma unroll
    for (int ct = 0; ct < 4; ct++) acc2[ct] = (floatx4){0.f, 0.f, 0.f, 0.f};
    for (int kc = 0; kc < 4; kc++) {
        short8 a = *(const short8*)(&zb[l15][kq + kc * 32]);
#pragma unroll
        for (int ct = 0; ct < 4; ct++) {
            const __hip_bfloat16* brow = WTgat + (size_t)(n0 + ct * 16 + l15) * 128 + kq;
            short8 b = *(const short8*)(brow + kc * 32);
            acc2[ct] = __builtin_amdgcn_mfma_f32_16x16x32_bf16(a, b, acc2[ct], 0, 0, 0);
        }
    }
    float spart[4] = {0.f, 0.f, 0.f, 0.f};
    float dpart[4] = {0.f, 0.f, 0.f, 0.f};
#pragma unroll
    for (int ct = 0; ct < 4; ct++) {
        int col = n0 + ct * 16 + l15;
        int cm  = col - 128 * h;
        float as_w = ldf(attS, h * CC + cm, f32);
        float ad_w = ldf(attD, h * CC + cm, f32);
#pragma unroll
        for (int r = 0; r < 4; r++) {
            float v = acc2[ct][r];
            HH[(size_t)(m0 + quad * 4 + r) * 256 + col] = __float2bfloat16(v);
            spart[r] += v * as_w;
            dpart[r] += v * ad_w;
        }
    }
#pragma unroll
    for (int o = 1; o <= 8; o <<= 1) {
#pragma unroll
        for (int r = 0; r < 4; r++) {
            spart[r] += __shfl_xor(spart[r], o);
            dpart[r] += __shfl_xor(dpart[r], o);
        }
    }
    if (l15 == 0) {
#pragma unroll
        for (int r = 0; r < 4; r++) {
            sS[w][quad * 4 + r] = spart[r];
            sD[w][quad * 4 + r] = dpart[r];
        }
    }
    __syncthreads();
    if (t < 32) {
        int row = t & 15, hh2 = t >> 4;
        AS[(m0 + row) * 2 + hh2] = sS[2 * hh2][row] + sS[2 * hh2 + 1][row];
        AD[(m0 + row) * 2 + hh2] = sD[2 * hh2][row] + sD[2 * hh2 + 1][row];
    }
}

// ---------------------------------------------------------------------------
// Fused decoder GEMM + GAT GEMM + attention scores (layer boundary t=0 -> t=1).
// ---------------------------------------------------------------------------
__global__ __launch_bounds__(256) void gemm_decatt_kernel(
    const __hip_bfloat16* __restrict__ A, const __hip_bfloat16* __restrict__ WTdec,
    const __hip_bfloat16* __restrict__ WTgat, const void* __restrict__ b_dec,
    __hip_bfloat16* __restrict__ HH,
    const void* __restrict__ attS, const void* __restrict__ attD,
    float* __restrict__ AS, float* __restrict__ AD, const int* __restrict__ flags)
{
    const int f32 = flags[0];
    __shared__ __hip_bfloat16 zo[32][136];
    int w = threadIdx.x >> 6, l = threadIdx.x & 63;
    int rt = w >> 1, cg = w & 1;
    int l15 = l & 15, quad = l >> 4, kq = quad * 8;
    int m0 = blockIdx.x * 32;

    // -------- phase 1: decoder GEMM --------
    {
        int n0 = cg * 64;
        const __hip_bfloat16* arow = A + (size_t)(m0 + rt * 16 + l15) * 256 + kq;
        floatx4 acc[4];
#pragma unroll
        for (int ct = 0; ct < 4; ct++) acc[ct] = (floatx4){0.f, 0.f, 0.f, 0.f};
        for (int kc = 0; kc < 8; kc++) {
            short8 a = *(const short8*)(arow + kc * 32);
#pragma unroll
            for (int ct = 0; ct < 4; ct++) {
                const __hip_bfloat16* brow = WTdec + (size_t)(n0 + ct * 16 + l15) * 256 + kq;
                short8 b = *(const short8*)(brow + kc * 32);
                acc[ct] = __builtin_amdgcn_mfma_f32_16x16x32_bf16(a, b, acc[ct], 0, 0, 0);
            }
        }
#pragma unroll
        for (int ct = 0; ct < 4; ct++) {
            int col = n0 + ct * 16 + l15;
            float bb = ldf(b_dec, col, f32);
#pragma unroll
            for (int r = 0; r < 4; r++)
                zo[rt * 16 + quad * 4 + r][col] = __float2bfloat16(acc[ct][r] + bb);
        }
    }
    __syncthreads();

    // -------- phase 2: GAT GEMM + attention (32-row/CG=2 geometry) --------
    int n0 = cg * 128;
    floatx4 acc2[8];
#pragma unroll
    for (int ct = 0; ct < 8; ct++) acc2[ct] = (floatx4){0.f, 0.f, 0.f, 0.f};
    for (int kc = 0; kc < 4; kc++) {
        short8 a = *(const short8*)(&zo[rt * 16 + l15][kq + kc * 32]);
#pragma unroll
        for (int ct = 0; ct < 8; ct++) {
            const __hip_bfloat16* brow = WTgat + (size_t)(n0 + ct * 16 + l15) * 128 + kq;
            short8 b = *(const short8*)(brow + kc * 32);
            acc2[ct] = __builtin_amdgcn_mfma_f32_16x16x32_bf16(a, b, acc2[ct], 0, 0, 0);
        }
    }
    float spart[4] = {0.f, 0.f, 0.f, 0.f};
    float dpart[4] = {0.f, 0.f, 0.f, 0.f};
#pragma unroll
    for (int ct = 0; ct < 8; ct++) {
        int cm  = ct * 16 + l15;           // column within head [0,128)
        int col = n0 + cm;
        float as_w = ldf(attS, cg * CC + cm, f32);
        float ad_w = ldf(attD, cg * CC + cm, f32);
#pragma unroll
        for (int r = 0; r < 4; r++) {
            float v = acc2[ct][r];
            HH[(size_t)(m0 + rt * 16 + quad * 4 + r) * 256 + col] = __float2bfloat16(v);
            spart[r] += v * as_w;
            dpart[r] += v * ad_w;
        }
    }
#pragma unroll
    for (int o = 1; o <= 8; o <<= 1) {
#pragma unroll
        for (int r = 0; r < 4; r++) {
            spart[r] += __shfl_xor(spart[r], o);
            dpart[r] += __shfl_xor(dpart[r], o);
        }
    }
    if (l15 == 0) {
#pragma unroll
        for (int r = 0; r < 4; r++) {
            int row = m0 + rt * 16 + quad * 4 + r;
            AS[row * 2 + cg] = spart[r];
            AD[row * 2 + cg] = dpart[r];
        }
    }
}

// ---------------------------------------------------------------------------
// Fused GAT softmax + aggregation, single-stats-pass + 8-deep MLP agg loop.
// Bucket CSR (ushort): base = d<<7, len = deg[d]. ALPHA bf16 planes.
// ---------------------------------------------------------------------------
__global__ __launch_bounds__(256) void gat_fused_kernel(
    const uint2* __restrict__ HH2,
    const float* __restrict__ AS, const float* __restrict__ AD,
    const int* __restrict__ deg, const unsigned short* __restrict__ csr,
    const void* __restrict__ b_gat, __hip_bfloat16* __restrict__ ALPHA,
    uint2* __restrict__ OUT2, const int* __restrict__ flags)
{
    const int f32 = flags[0];
    int d = (blockIdx.x * blockDim.x + threadIdx.x) >> 6;
    int l = threadIdx.x & 63;
    if (d >= NN) return;
    int h = l >> 5, j = l & 31;
    int b = d << 7;
    int e = b + min(deg[d], CAP);
    float adh = AD[d * 2 + h];
    float self_e = expf(leaky02(AS[d * 2 + h] + adh));
    __hip_bfloat16* __restrict__ AH = ALPHA + (size_t)h * (NN * CAP);

    // single stats pass: exp(leaky logits) -> bf16 ALPHA plane + running sum
    float sum = (j == 0) ? self_e : 0.f;
    for (int i = b + j; i < e; i += 32) {
        float ex = expf(leaky02(AS[(int)csr[i] * 2 + h] + adh));
        __hip_bfloat16 exb = __float2bfloat16(ex);
        AH[i] = exb;
        sum += __bfloat162float(exb);
    }
#pragma unroll
    for (int o = 16; o; o >>= 1) sum += __shfl_xor(sum, o);   // within half
    float inv = 1.f / sum;

    // aggregation: lane l covers cols 4l..4l+3; accumulate unnormalized
    uint2 wv = HH2[(size_t)d * 64 + l];
    float4 p = bf4(wv.x, wv.y);
    float4 acc = make_float4(self_e * p.x, self_e * p.y, self_e * p.z, self_e * p.w);
    int i = b;
    for (; i + 8 <= e; i += 8) {
        int s0 = csr[i],     s1 = csr[i + 1], s2 = csr[i + 2], s3 = csr[i + 3];
        int s4 = csr[i + 4], s5 = csr[i + 5], s6 = csr[i + 6], s7 = csr[i + 7];
        float a1 = b2f(AH[i]),     a2 = b2f(AH[i + 1]), a3 = b2f(AH[i + 2]), a4 = b2f(AH[i + 3]);
        float a5 = b2f(AH[i + 4]), a6 = b2f(AH[i + 5]), a7 = b2f(AH[i + 6]), a8 = b2f(AH[i + 7]);
        uint2 w0 = HH2[(size_t)s0 * 64 + l];
        uint2 w1 = HH2[(size_t)s1 * 64 + l];
        uint2 w2 = HH2[(size_t)s2 * 64 + l];
        uint2 w3 = HH2[(size_t)s3 * 64 + l];
        uint2 w4 = HH2[(size_t)s4 * 64 + l];
        uint2 w5 = HH2[(size_t)s5 * 64 + l];
        uint2 w6 = HH2[(size_t)s6 * 64 + l];
        uint2 w7 = HH2[(size_t)s7 * 64 + l];
        float4 f;
        f = bf4(w0.x, w0.y); acc.x += a1 * f.x; acc.y += a1 * f.y; acc.z += a1 * f.z; acc.w += a1 * f.w;
        f = bf4(w1.x, w1.y); acc.x += a2 * f.x; acc.y += a2 * f.y; acc.z += a2 * f.z; acc.w += a2 * f.w;
        f = bf4(w2.x, w2.y); acc.x += a3 * f.x; acc.y += a3 * f.y; acc.z += a3 * f.z; acc.w += a3 * f.w;
        f = bf4(w3.x, w3.y); acc.x += a4 * f.x; acc.y += a4 * f.y; acc.z += a4 * f.z; acc.w += a4 * f.w;
        f = bf4(w4.x, w4.y); acc.x += a5 * f.x; acc.y += a5 * f.y; acc.z += a5 * f.z; acc.w += a5 * f.w;
        f = bf4(w5.x, w5.y); acc.x += a6 * f.x; acc.y += a6 * f.y; acc.z += a6 * f.z; acc.w += a6 * f.w;
        f = bf4(w6.x, w6.y); acc.x += a7 * f.x; acc.y += a7 * f.y; acc.z += a7 * f.z; acc.w += a7 * f.w;
        f = bf4(w7.x, w7.y); acc.x += a8 * f.x; acc.y += a8 * f.y; acc.z += a8 * f.z; acc.w += a8 * f.w;
    }
    for (; i + 4 <= e; i += 4) {
        int s0 = csr[i], s1 = csr[i + 1], s2 = csr[i + 2], s3 = csr[i + 3];
        float a1 = b2f(AH[i]), a2 = b2f(AH[i + 1]), a3 = b2f(AH[i + 2]), a4 = b2f(AH[i + 3]);
        uint2 w0 = HH2[(size_t)s0 * 64 + l];
        uint2 w1 = HH2[(size_t)s1 * 64 + l];
        uint2 w2 = HH2[(size_t)s2 * 64 + l];
        uint2 w3 = HH2[(size_t)s3 * 64 + l];
        float4 f;
        f = bf4(w0.x, w0.y); acc.x += a1 * f.x; acc.y += a1 * f.y; acc.z += a1 * f.z; acc.w += a1 * f.w;
        f = bf4(w1.x, w1.y); acc.x += a2 * f.x; acc.y += a2 * f.y; acc.z += a2 * f.z; acc.w += a2 * f.w;
        f = bf4(w2.x, w2.y); acc.x += a3 * f.x; acc.y += a3 * f.y; acc.z += a3 * f.z; acc.w += a3 * f.w;
        f = bf4(w3.x, w3.y); acc.x += a4 * f.x; acc.y += a4 * f.y; acc.z += a4 * f.z; acc.w += a4 * f.w;
    }
    for (; i < e; i++) {
        int s = csr[i];
        float al = b2f(AH[i]);
        uint2 wq = HH2[(size_t)s * 64 + l];
        float4 f = bf4(wq.x, wq.y);
        acc.x += al * f.x; acc.y += al * f.y; acc.z += al * f.z; acc.w += al * f.w;
    }
    int c0 = 4 * l;
    acc.x = acc.x * inv + ldf(b_gat, c0 + 0, f32);
    acc.y = acc.y * inv + ldf(b_gat, c0 + 1, f32);
    acc.z = acc.z * inv + ldf(b_gat, c0 + 2, f32);
    acc.w = acc.w * inv + ldf(b_gat, c0 + 3, f32);
    OUT2[(size_t)d * 64 + l] = f4bf(acc);
}

// ---------------------------------------------------------------------------
extern "C" void kernel_launch(void* const* d_in, const int* in_sizes, int n_in,
                              void* d_out, int out_size, void* d_ws, size_t ws_size,
                              hipStream_t stream)
{
    const void* xin    = d_in[0];
    const void* ei     = d_in[1];
    const void* eps    = d_in[2];
    const void* W_emb  = d_in[3];
    const void* b_emb  = d_in[4];
    const void* g_emb  = d_in[5];
    const void* be_emb = d_in[6];
    const void* W1     = d_in[7];
    const void* b1     = d_in[8];
    const void* g1     = d_in[9];
    const void* be1    = d_in[10];
    const void* W2     = d_in[11];
    const void* b2     = d_in[12];
    const void* W_mu   = d_in[13];
    const void* b_mu   = d_in[14];
    const void* W_var  = d_in[15];
    const void* b_var  = d_in[16];
    const void* W_gat  = d_in[17];
    const void* attS   = d_in[18];
    const void* attD   = d_in[19];
    const void* b_gat  = d_in[20];
    const void* W_dec  = d_in[21];
    const void* b_dec  = d_in[22];

    // workspace layout
    float* ws = (float*)d_ws;
    const size_t NB = (size_t)NN * CC;       // 2,560,000
    float* B0 = ws;                          // bf16 HH (N x 256)
    float* B1 = ws + 1 * NB;                 // bf16 Y | OUT (N x 256)
    float* B2 = ws + 2 * NB;                 // bf16 Xbf | Hbf
    __hip_bfloat16* Xbf   = (__hip_bfloat16*)B2;       // N x 128
    __hip_bfloat16* Hbf   = Xbf + NB;                  // N x 128 (W1 t=0 out)
    __hip_bfloat16* HHbf  = (__hip_bfloat16*)B0;       // N x 256
    __hip_bfloat16* OUTbf = (__hip_bfloat16*)B1;       // N x 256
    __hip_bfloat16* Ybf   = (__hip_bfloat16*)B1;       // N x 128 (pre-BN Y; W1 t=1 out)
    float* TAIL = ws + 4 * NB;
    float* AS      = TAIL;                        // 40000
    float* AD      = TAIL + 40000;                // 40000
    int*   FLAGS   = (int*)(TAIL + 80000);        // 16
    float* SUMSALL = (float*)(FLAGS + 16);        // 3 x 256 (zeroed by memset)
    int*   DEG     = (int*)(SUMSALL + 768);       // 20000 (zeroed by memset)
    float* PART    = (float*)(DEG + 20000);       // 1250*512 = 640000
    unsigned short* CSR16 = (unsigned short*)(PART + 640000);  // NN*CAP ushort
    __hip_bfloat16* ALPHAb = (__hip_bfloat16*)((float*)(PART + 640000) + NN * CAP / 2);
    __hip_bfloat16* WTB = (__hip_bfloat16*)((float*)(PART + 640000) + NN * CAP / 2 + NN * CAP);
    __hip_bfloat16* WTemb = WTB;
    __hip_bfloat16* WT1   = WTB + R0_;
    __hip_bfloat16* WT2   = WTB + R1_;
    __hip_bfloat16* WTmuv = WTB + R2_;       // mu|var contiguous -> NC=256
    __hip_bfloat16* WTgat = WTB + R4_;
    __hip_bfloat16* WTdec = WTB + R5_;
    __hip_bfloat16* Xin   = WTB + R6_;       // NN x 96 bf16

    const int GEMM_BLKS = NN / 32;           // 625

    // -------- memset: SUMSALL + DEG (contiguous) --------
    hipMemsetAsync(SUMSALL, 0, (768 + 20000) * sizeof(int), stream);

    // -------- conversion ∥ region-partitioned bucket scatter (merged) --------
    cvt_scatter_kernel<<<HB + CVTB, 256, 0, stream>>>(
        W_emb, W1, W2, W_mu, W_var, W_gat, W_dec, xin,
        (const unsigned*)ei, WTB, FLAGS, DEG, CSR16);

    // -------- Stage A: Y = x @ W_emb + b_emb (+ BN-stats partials) ----------
    mfma_gemm_kernel<96, 128, 2, 1, 1, 0><<<GEMM_BLKS, 256, 0, stream>>>(
        Xin, WTemb, b_emb, Ybf, 0, PART, nullptr, nullptr, nullptr, FLAGS);
    bn_reduce_kernel<<<8, 256, 0, stream>>>(PART, SUMSALL, GEMM_BLKS);

    // -------- Stage B: GIN x2 (gather fused into W1; buffers ping-pong
    //          because the gather reads RANDOM rows of its input) -----------
    // t=0: Ybf -(gather+BN_A+W1)-> Hbf; reduce; Hbf -(BN_A+W2)-> Xbf
    gemm_gin_kernel<1><<<NN / 16, 256, 0, stream>>>(
        (const uint2*)Ybf, WT1, b1, Hbf, PART, DEG, CSR16,
        SUMSALL, g_emb, be_emb, FLAGS);
    bn_reduce_kernel<<<8, 256, 0, stream>>>(PART, SUMSALL + 256, NN / 16);
    mfma_gemm_kernel<128, 128, 2, 1, 0, 1><<<GEMM_BLKS, 256, 0, stream>>>(
        Hbf, WT2, b2, Xbf, 0, nullptr, SUMSALL + 256, g1, be1, FLAGS);
    // t=1: Xbf -(gather+W1)-> Ybf; reduce; Ybf -(BN_A+W2)-> Xbf
    gemm_gin_kernel<0><<<NN / 16, 256, 0, stream>>>(
        (const uint2*)Xbf, WT1, b1, Ybf, PART, DEG, CSR16,
        nullptr, nullptr, nullptr, FLAGS);
    bn_reduce_kernel<<<8, 256, 0, stream>>>(PART, SUMSALL + 512, NN / 16);
    mfma_gemm_kernel<128, 128, 2, 1, 0, 1><<<GEMM_BLKS, 256, 0, stream>>>(
        Ybf, WT2, b2, Xbf, 0, nullptr, SUMSALL + 512, g1, be1, FLAGS);

    // -------- Stage C+D0: VAE heads + reparam + GAT GEMM t=0, fused ---------
    gemm_zatt_kernel<<<NN / 16, 256, 0, stream>>>(
        Xbf, WTmuv, WTgat, eps, b_mu, b_var, HHbf, attS, attD, AS, AD, d_out, FLAGS);
    gat_fused_kernel<<<(NN * 64) / 256, 256, 0, stream>>>(
        (const uint2*)HHbf, AS, AD, DEG, CSR16, b_gat, ALPHAb, (uint2*)OUTbf, FLAGS);

    // -------- dec t=0 + GAT GEMM t=1, fused ---------------------------------
    gemm_decatt_kernel<<<GEMM_BLKS, 256, 0, stream>>>(
        OUTbf, WTdec, WTgat, b_dec, HHbf, attS, attD, AS, AD, FLAGS);
    gat_fused_kernel<<<(NN * 64) / 256, 256, 0, stream>>>(
        (const uint2*)HHbf, AS, AD, DEG, CSR16, b_gat, ALPHAb, (uint2*)OUTbf, FLAGS);

    // -------- final decoder -> d_out (zout) ---------------------------------
    mfma_gemm_kernel<256, 128, 2, 2, 0, 0><<<GEMM_BLKS, 256, 0, stream>>>(
        OUTbf, WTdec, b_dec, d_out, NN * CC, nullptr, nullptr, nullptr, nullptr, FLAGS);
}

// Round 14
// 410.884 us; speedup vs baseline: 1.2475x; 1.2475x over previous
//
#include <hip/hip_runtime.h>
#include <hip/hip_bf16.h>

// Problem constants
#define NN   20000          // nodes
#define DIN_ 92             // atom feature dim
#define CC   128            // hidden dim
#define EE   640000         // edges (self loops handled explicitly)
#define CAP  128            // adjacency bucket capacity (deg ~ Poisson(32); P(>128) ~ 0)
#define BN_EPS 1e-5f

typedef short short8 __attribute__((ext_vector_type(8)));
typedef float floatx4 __attribute__((ext_vector_type(4)));

// ---------------------------------------------------------------------------
// Dual-dtype helpers: flags[0]=1 -> external floats are fp32 (else bf16)
//                     flags[1]=1 -> edge_index is int64 (else int32)
// ---------------------------------------------------------------------------
static __device__ __forceinline__ float b2f(__hip_bfloat16 v) { return __bfloat162float(v); }
static __device__ __forceinline__ float ldf(const void* p, int i, int f32) {
    return f32 ? ((const float*)p)[i]
               : __bfloat162float(((const __hip_bfloat16*)p)[i]);
}
static __device__ __forceinline__ void stf(void* p, int i, float v, int f32) {
    if (f32) ((float*)p)[i] = v;
    else     ((__hip_bfloat16*)p)[i] = __float2bfloat16(v);
}
static __device__ __forceinline__ float leaky02(float x) { return x > 0.f ? x : 0.2f * x; }

// bf16 decode via bit ops (bf16 = top half of fp32)
static __device__ __forceinline__ float2 bfp(unsigned w) {
    return make_float2(__uint_as_float(w << 16), __uint_as_float(w & 0xffff0000u));
}
static __device__ __forceinline__ float4 bf4(unsigned x, unsigned y) {
    return make_float4(__uint_as_float(x << 16), __uint_as_float(x & 0xffff0000u),
                       __uint_as_float(y << 16), __uint_as_float(y & 0xffff0000u));
}
static __device__ __forceinline__ uint2 f4bf(float4 v) {
    union { uint2 u; __hip_bfloat16 b[4]; } x;
    x.b[0] = __float2bfloat16(v.x); x.b[1] = __float2bfloat16(v.y);
    x.b[2] = __float2bfloat16(v.z); x.b[3] = __float2bfloat16(v.w);
    return x.u;
}
static __device__ __forceinline__ unsigned f2bf(float2 v) {
    union { unsigned u; __hip_bfloat16 b[2]; } x;
    x.b[0] = __float2bfloat16(v.x); x.b[1] = __float2bfloat16(v.y);
    return x.u;
}
static __device__ __forceinline__ short bf16s(float v) {
    union { __hip_bfloat16 b; unsigned short u; } cv;
    cv.b = __float2bfloat16(v);
    return (short)cv.u;
}

// ---------------------------------------------------------------------------
// Merged conversion + region-partitioned bucket scatter (block-role split).
// Blocks [0, HB): scatter role — edges whose dst region (d/2500) matches
//   blockIdx&7 -> csr16[d*CAP + atomicAdd(&deg[d],1)] = s. Region
//   partitioning keeps bucket writes XCD-local (r10: global version had
//   ~8x HBM write amplification from non-coherent per-XCD L2s).
// Blocks [HB, HB+CVTB): conversion role; first cvt block publishes FLAGS.
// DEG zeroed by a memset BEFORE this kernel.
// ---------------------------------------------------------------------------
#define R0_ 12288
#define R1_ (R0_ + 16384)
#define R2_ (R1_ + 16384)
#define R3_ (R2_ + 16384)
#define R4_ (R3_ + 16384)
#define R5_ (R4_ + 32768)
#define R6_ (R5_ + 32768)          // 143360 weight elements
#define TCVT (R6_ + NN * 96)       // + node features
#define CHUNK 2048
#define NCH ((EE + CHUNK - 1) / CHUNK)   // 313 chunks
#define HB (NCH * 8)               // 2504 scatter blocks
#define CVTB ((TCVT + 255) / 256)  // cvt blocks

__global__ __launch_bounds__(256) void cvt_scatter_kernel(
    const void* __restrict__ w_emb, const void* __restrict__ w1,
    const void* __restrict__ w2, const void* __restrict__ wmu,
    const void* __restrict__ wvar, const void* __restrict__ wgat,
    const void* __restrict__ wdec, const void* __restrict__ xin,
    const unsigned* __restrict__ ei,
    __hip_bfloat16* __restrict__ dst,
    int* __restrict__ flags, int* __restrict__ deg,
    unsigned short* __restrict__ csr)
{
    if ((int)blockIdx.x < HB) {
        // -------- scatter role --------
        __shared__ int cz;
        if (threadIdx.x == 0) cz = 0;
        __syncthreads();
        if (ei[2 * threadIdx.x + 1] == 0u) atomicAdd(&cz, 1);
        __syncthreads();
        const int i64 = (cz >= 250);
        int r = blockIdx.x & 7;
        int c = blockIdx.x >> 3;
        int base = c * CHUNK + threadIdx.x;
#pragma unroll
        for (int k = 0; k < CHUNK / 256; k++) {
            int e = base + k * 256;
            if (e < EE) {
                int d = i64 ? (int)((const long long*)ei)[EE + e] : ((const int*)ei)[EE + e];
                if (d / 2500 == r) {
                    int s = i64 ? (int)((const long long*)ei)[e] : ((const int*)ei)[e];
                    int pos = atomicAdd(&deg[d], 1);
                    if (pos < CAP) csr[(d << 7) + pos] = (unsigned short)s;
                }
            }
        }
        return;
    }

    // -------- conversion role --------
    __shared__ int cnt_band, cnt_zero;
    if (threadIdx.x == 0) { cnt_band = 0; cnt_zero = 0; }
    __syncthreads();
    {
        unsigned wv = ((const unsigned*)xin)[threadIdx.x];
        unsigned eb = ((wv & 0xFFFFu) >> 7) & 0xFFu;
        if (eb >= 90u && eb <= 140u) atomicAdd(&cnt_band, 1);
        if ((int)blockIdx.x == HB && ei[2 * threadIdx.x + 1] == 0u) atomicAdd(&cnt_zero, 1);
    }
    __syncthreads();
    const int f32 = (cnt_band < 200) ? 1 : 0;
    if ((int)blockIdx.x == HB && threadIdx.x == 0) {
        flags[0] = f32;
        flags[1] = (cnt_zero >= 250) ? 1 : 0;
    }

    int i = ((int)blockIdx.x - HB) * 256 + threadIdx.x;
    if (i >= TCVT) return;
    float v;
    if (i < R0_) {
        int n = i / 96, k = i - n * 96;
        v = (k < DIN_) ? ldf(w_emb, k * 128 + n, f32) : 0.f;
    } else if (i < R1_) {
        int j = i - R0_; int n = j >> 7, k = j & 127; v = ldf(w1, k * 128 + n, f32);
    } else if (i < R2_) {
        int j = i - R1_; int n = j >> 7, k = j & 127; v = ldf(w2, k * 128 + n, f32);
    } else if (i < R3_) {
        int j = i - R2_; int n = j >> 7, k = j & 127; v = ldf(wmu, k * 128 + n, f32);
    } else if (i < R4_) {
        int j = i - R3_; int n = j >> 7, k = j & 127; v = ldf(wvar, k * 128 + n, f32);
    } else if (i < R5_) {
        int j = i - R4_; int n = j >> 7, k = j & 127; v = ldf(wgat, k * 256 + n, f32);
    } else if (i < R6_) {
        int j = i - R5_; int n = j >> 8, k = j & 255; v = ldf(wdec, k * 128 + n, f32);
    } else {
        int j = i - R6_; int row = j / 96, k = j - row * 96;
        v = (k < DIN_) ? ldf(xin, row * DIN_ + k, f32) : 0.f;
    }
    dst[i] = __float2bfloat16(v);
}

// ---------------------------------------------------------------------------
// MFMA GEMM (16x16x32 bf16): C[M,NC] = A @ W + bias.
// STATS=1: per-column sum/sumsq quad-reduced via shfl_xor, written as
//   NON-ATOMIC per-block partials (r11: direct atomicAdd = 1250 serialized
//   device-atomics per address ~ 44 us tail; partials + reduce ~40x cheaper).
// BN_A=1 : fused BN+ReLU on the A-load path.
// ---------------------------------------------------------------------------
template<int KP, int NC, int CG, int OUT_MODE, int STATS, int BN_A>
__global__ __launch_bounds__(256) void mfma_gemm_kernel(
    const __hip_bfloat16* __restrict__ A,
    const __hip_bfloat16* __restrict__ WT,
    const void* __restrict__ bias,
    void* __restrict__ Cout, int out_off, float* __restrict__ part,
    const float* __restrict__ bnsums, const void* __restrict__ bng,
    const void* __restrict__ bnbe, const int* __restrict__ flags)
{
    const int f32 = flags[0];
    constexpr int MB = 16 * (4 / CG);
    constexpr int CT = NC / (16 * CG);
    __shared__ float sc_s[128], sh_s[128];
    if (BN_A) {
        int t = threadIdx.x;
        if (t < 128) {
            float mean = bnsums[t] * (1.f / NN);
            float var  = bnsums[128 + t] * (1.f / NN) - mean * mean;
            float rs   = rsqrtf(fmaxf(var, 0.f) + BN_EPS);
            float g    = ldf(bng, t, f32);
            float sc   = rs * g;
            sc_s[t] = sc;
            sh_s[t] = ldf(bnbe, t, f32) - mean * sc;
        }
        __syncthreads();
    }
    int w = threadIdx.x >> 6, l = threadIdx.x & 63;
    int rt = w / CG, cg = w - rt * CG;
    int m0 = blockIdx.x * MB + rt * 16;
    int n0 = cg * (16 * CT);
    int l15 = l & 15, kq = (l >> 4) * 8;
    const __hip_bfloat16* arow = A + (size_t)(m0 + l15) * KP + kq;

    floatx4 acc[CT];
#pragma unroll
    for (int ct = 0; ct < CT; ct++) acc[ct] = (floatx4){0.f, 0.f, 0.f, 0.f};

    for (int kc = 0; kc < KP / 32; kc++) {
        short8 a = *(const short8*)(arow + kc * 32);
        if (BN_A) {
#pragma unroll
            for (int k = 0; k < 8; k++) {
                int c = kq + kc * 32 + k;
                float v = __uint_as_float(((unsigned)(unsigned short)a[k]) << 16);
                float o = v * sc_s[c] + sh_s[c];
                a[k] = bf16s(o > 0.f ? o : 0.f);
            }
        }
#pragma unroll
        for (int ct = 0; ct < CT; ct++) {
            const __hip_bfloat16* brow = WT + (size_t)(n0 + ct * 16 + l15) * KP + kq;
            short8 b = *(const short8*)(brow + kc * 32);
            acc[ct] = __builtin_amdgcn_mfma_f32_16x16x32_bf16(a, b, acc[ct], 0, 0, 0);
        }
    }

    int quad = l >> 4;
#pragma unroll
    for (int ct = 0; ct < CT; ct++) {
        int col = n0 + ct * 16 + l15;
        float bb = bias ? ldf(bias, col, f32) : 0.f;
        float sl = 0.f, ql = 0.f;
#pragma unroll
        for (int r = 0; r < 4; r++) {
            int row = m0 + quad * 4 + r;
            float v = acc[ct][r] + bb;
            size_t o = (size_t)row * NC + col;
            if (OUT_MODE == 0)      ((float*)Cout)[o] = v;
            else if (OUT_MODE == 1) ((__hip_bfloat16*)Cout)[o] = __float2bfloat16(v);
            else                    stf(Cout, out_off + (int)o, v, f32);
            if (STATS) { sl += v; ql += v * v; }
        }
        if (STATS) {
            sl += __shfl_xor(sl, 16); sl += __shfl_xor(sl, 32);
            ql += __shfl_xor(ql, 16); ql += __shfl_xor(ql, 32);
            if (quad == 0) {
                part[blockIdx.x * 512 + rt * 256 + col] = sl;
                part[blockIdx.x * 512 + rt * 256 + 128 + col] = ql;
            }
        }
    }
}

// ---------------------------------------------------------------------------
// Fused GIN gather + W1 GEMM (16-row blocks; gather into LDS then MFMA).
// STATS partials: single half only (blk*512 + {col,128+col}); reduced with
// TWOHALF=0 (no zero-fill needed).
// ---------------------------------------------------------------------------
template<int BN_A>
__global__ __launch_bounds__(256) void gemm_gin_kernel(
    const uint2* __restrict__ X2, const __hip_bfloat16* __restrict__ WT,
    const void* __restrict__ bias, __hip_bfloat16* __restrict__ Cout,
    float* __restrict__ part,
    const int* __restrict__ deg, const unsigned short* __restrict__ csr,
    const float* __restrict__ bnsums, const void* __restrict__ bng,
    const void* __restrict__ bnbe, const int* __restrict__ flags)
{
    const int f32 = flags[0];
    __shared__ __hip_bfloat16 ab[16][136];
    __shared__ float sc_s[128], sh_s[128];
    int t = threadIdx.x;
    if (BN_A) {
        if (t < 128) {
            float mean = bnsums[t] * (1.f / NN);
            float var  = bnsums[128 + t] * (1.f / NN) - mean * mean;
            float rs   = rsqrtf(fmaxf(var, 0.f) + BN_EPS);
            float g    = ldf(bng, t, f32);
            float sc   = rs * g;
            sc_s[t] = sc;
            sh_s[t] = ldf(bnbe, t, f32) - mean * sc;
        }
        __syncthreads();
    }
    int m0 = blockIdx.x * 16;

    // ---- phase 1: gather (8 half-waves x 2 dsts) ----
    int hwl = t >> 5;            // 0..7
    int l5  = t & 31;
    int c4  = 4 * l5;
    float sc0 = 0.f, sc1 = 0.f, sc2 = 0.f, sc3 = 0.f;
    float sh0 = 0.f, sh1 = 0.f, sh2 = 0.f, sh3 = 0.f;
    if (BN_A) {
        sc0 = sc_s[c4 + 0]; sc1 = sc_s[c4 + 1]; sc2 = sc_s[c4 + 2]; sc3 = sc_s[c4 + 3];
        sh0 = sh_s[c4 + 0]; sh1 = sh_s[c4 + 1]; sh2 = sh_s[c4 + 2]; sh3 = sh_s[c4 + 3];
    }
#define GBNR(f) do { if (BN_A) { \
    f.x = fmaxf(f.x * sc0 + sh0, 0.f); \
    f.y = fmaxf(f.y * sc1 + sh1, 0.f); \
    f.z = fmaxf(f.z * sc2 + sh2, 0.f); \
    f.w = fmaxf(f.w * sc3 + sh3, 0.f); } } while (0)
#pragma unroll
    for (int q = 0; q < 2; q++) {
        int row = hwl * 2 + q;
        int d = m0 + row;
        uint2 w0 = X2[(size_t)d * 32 + l5];
        float4 acc = bf4(w0.x, w0.y);
        GBNR(acc);
        int b = d << 7;
        int e = b + min(deg[d], CAP);
        int i = b;
        for (; i + 4 <= e; i += 4) {
            int s0 = csr[i], s1 = csr[i + 1], s2 = csr[i + 2], s3 = csr[i + 3];
            uint2 a0 = X2[(size_t)s0 * 32 + l5];
            uint2 a1 = X2[(size_t)s1 * 32 + l5];
            uint2 a2 = X2[(size_t)s2 * 32 + l5];
            uint2 a3 = X2[(size_t)s3 * 32 + l5];
            float4 f0 = bf4(a0.x, a0.y), f1 = bf4(a1.x, a1.y);
            float4 f2 = bf4(a2.x, a2.y), f3 = bf4(a3.x, a3.y);
            GBNR(f0); GBNR(f1); GBNR(f2); GBNR(f3);
            acc.x += f0.x + f1.x + f2.x + f3.x;
            acc.y += f0.y + f1.y + f2.y + f3.y;
            acc.z += f0.z + f1.z + f2.z + f3.z;
            acc.w += f0.w + f1.w + f2.w + f3.w;
        }
        for (; i < e; i++) {
            uint2 a = X2[(size_t)csr[i] * 32 + l5];
            float4 f = bf4(a.x, a.y);
            GBNR(f);
            acc.x += f.x; acc.y += f.y; acc.z += f.z; acc.w += f.w;
        }
        ab[row][c4 + 0] = __float2bfloat16(acc.x);
        ab[row][c4 + 1] = __float2bfloat16(acc.y);
        ab[row][c4 + 2] = __float2bfloat16(acc.z);
        ab[row][c4 + 3] = __float2bfloat16(acc.w);
    }
#undef GBNR
    __syncthreads();

    // ---- phase 2: MFMA (16 rows, CG=4: wave w covers cols w*32, CT=2) ----
    int w = t >> 6, l = t & 63;
    int n0 = w * 32;
    int l15 = l & 15, quad = l >> 4, kq = quad * 8;
    floatx4 acc[2];
    acc[0] = (floatx4){0.f, 0.f, 0.f, 0.f};
    acc[1] = (floatx4){0.f, 0.f, 0.f, 0.f};
    for (int kc = 0; kc < 4; kc++) {
        short8 a = *(const short8*)(&ab[l15][kq + kc * 32]);
#pragma unroll
        for (int ct = 0; ct < 2; ct++) {
            const __hip_bfloat16* brow = WT + (size_t)(n0 + ct * 16 + l15) * 128 + kq;
            short8 b = *(const short8*)(brow + kc * 32);
            acc[ct] = __builtin_amdgcn_mfma_f32_16x16x32_bf16(a, b, acc[ct], 0, 0, 0);
        }
    }
#pragma unroll
    for (int ct = 0; ct < 2; ct++) {
        int col = n0 + ct * 16 + l15;
        float bb = ldf(bias, col, f32);
        float sl = 0.f, ql = 0.f;
#pragma unroll
        for (int r = 0; r < 4; r++) {
            int row = m0 + quad * 4 + r;
            float v = acc[ct][r] + bb;
            Cout[(size_t)row * 128 + col] = __float2bfloat16(v);
            sl += v; ql += v * v;
        }
        sl += __shfl_xor(sl, 16); sl += __shfl_xor(sl, 32);
        ql += __shfl_xor(ql, 16); ql += __shfl_xor(ql, 32);
        if (quad == 0) {
            part[blockIdx.x * 512 + col] = sl;
            part[blockIdx.x * 512 + 128 + col] = ql;
        }
    }
}

// ---------------------------------------------------------------------------
// Reduce per-block BN partials -> sums[256] (sum | sumsq).
// COLUMN-PARALLEL: one block per output column c (grid 256); thread t sums
// partial-blocks t, t+256, ... (<=5 iters at nblk=1250), then intra-block
// shfl+LDS reduce, single plain store.
// (r13 post-mortem: the old 8-block design ran a SERIAL 157-iteration load
// loop per thread at 1 wave/SIMD — ~47 us of pure memory latency, all
// counters ~0. Latency-parallel layout: ~65K threads, ~4 us.)
// TWOHALF: add the +256 half (32-row STATS GEMMs); gemm_gin uses 0.
// ---------------------------------------------------------------------------
template<int TWOHALF>
__global__ __launch_bounds__(256) void bn_reduce_kernel(
    const float* __restrict__ part, float* __restrict__ sums, int nblk)
{
    int c = blockIdx.x;           // 0..255
    int t = threadIdx.x;
    float v = 0.f;
    for (int p = t; p < nblk; p += 256) {
        v += part[p * 512 + c];
        if (TWOHALF) v += part[p * 512 + 256 + c];
    }
#pragma unroll
    for (int o = 32; o; o >>= 1) v += __shfl_down(v, o);
    __shared__ float s[4];
    if ((t & 63) == 0) s[t >> 6] = v;
    __syncthreads();
    if (t == 0) sums[c] = s[0] + s[1] + s[2] + s[3];
}

// ---------------------------------------------------------------------------
// Fused VAE-head GEMM + reparameterization + GAT GEMM + attention scores.
// ---------------------------------------------------------------------------
__global__ __launch_bounds__(256) void gemm_zatt_kernel(
    const __hip_bfloat16* __restrict__ A, const __hip_bfloat16* __restrict__ WTmuv,
    const __hip_bfloat16* __restrict__ WTgat,
    const void* __restrict__ eps, const void* __restrict__ b_mu, const void* __restrict__ b_var,
    __hip_bfloat16* __restrict__ HH,
    const void* __restrict__ attS, const void* __restrict__ attD,
    float* __restrict__ AS, float* __restrict__ AD,
    void* __restrict__ out, const int* __restrict__ flags)
{
    const int f32 = flags[0];
    __shared__ float zs[16][257];
    __shared__ __hip_bfloat16 zb[16][136];
    __shared__ float sS[4][16], sD[4][16];
    int w = threadIdx.x >> 6, l = threadIdx.x & 63;
    int m0 = blockIdx.x * 16;
    int n0 = w * 64;
    int l15 = l & 15, quad = l >> 4, kq = quad * 8;
    const __hip_bfloat16* arow = A + (size_t)(m0 + l15) * 128 + kq;

    // -------- phase 1: mu|logvar GEMM --------
    floatx4 acc[4];
#pragma unroll
    for (int ct = 0; ct < 4; ct++) acc[ct] = (floatx4){0.f, 0.f, 0.f, 0.f};
    for (int kc = 0; kc < 4; kc++) {
        short8 a = *(const short8*)(arow + kc * 32);
#pragma unroll
        for (int ct = 0; ct < 4; ct++) {
            const __hip_bfloat16* brow = WTmuv + (size_t)(n0 + ct * 16 + l15) * 128 + kq;
            short8 b = *(const short8*)(brow + kc * 32);
            acc[ct] = __builtin_amdgcn_mfma_f32_16x16x32_bf16(a, b, acc[ct], 0, 0, 0);
        }
    }
#pragma unroll
    for (int ct = 0; ct < 4; ct++) {
#pragma unroll
        for (int r = 0; r < 4; r++)
            zs[quad * 4 + r][n0 + ct * 16 + l15] = acc[ct][r];
    }
    __syncthreads();
    int t = threadIdx.x;
    const int NB2 = NN * CC;
#pragma unroll
    for (int k = 0; k < 8; k++) {
        int idx = k * 256 + t;
        int row = idx >> 7, c = idx & 127;
        float mu = zs[row][c]       + ldf(b_mu,  c, f32);
        float lv = zs[row][128 + c] + ldf(b_var, c, f32);
        int gi = (m0 + row) * 128 + c;
        float z = ldf(eps, gi, f32) * expf(0.5f * lv) + mu;
        zb[row][c] = __float2bfloat16(z);
        stf(out, gi, z, f32);                 // zin
        stf(out, 2 * NB2 + gi, mu, f32);      // mu
        stf(out, 3 * NB2 + gi, lv, f32);      // logvar
    }
    __syncthreads();

    // -------- phase 2: GAT GEMM + attention epilogue --------
    int h = w >> 1;
    floatx4 acc2[4];
#pragma unroll
    for (int ct = 0; ct < 4; ct++) acc2[ct] = (floatx4){0.f, 0.f, 0.f, 0.f};
    for (int kc = 0; kc < 4; kc++) {
        short8 a = *(const short8*)(&zb[l15][kq + kc * 32]);
#pragma unroll
        for (int ct = 0; ct < 4; ct++) {
            const __hip_bfloat16* brow = WTgat + (size_t)(n0 + ct * 16 + l15) * 128 + kq;
            short8 b = *(const short8*)(brow + kc * 32);
            acc2[ct] = __builtin_amdgcn_mfma_f32_16x16x32_bf16(a, b, acc2[ct], 0, 0, 0);
        }
    }
    float spart[4] = {0.f, 0.f, 0.f, 0.f};
    float dpart[4] = {0.f, 0.f, 0.f, 0.f};
#pragma unroll
    for (int ct = 0; ct < 4; ct++) {
        int col = n0 + ct * 16 + l15;
        int cm  = col - 128 * h;
        float as_w = ldf(attS, h * CC + cm, f32);
        float ad_w = ldf(attD, h * CC + cm, f32);
#pragma unroll
        for (int r = 0; r < 4; r++) {
            float v = acc2[ct][r];
            HH[(size_t)(m0 + quad * 4 + r) * 256 + col] = __float2bfloat16(v);
            spart[r] += v * as_w;
            dpart[r] += v * ad_w;
        }
    }
#pragma unroll
    for (int o = 1; o <= 8; o <<= 1) {
#pragma unroll
        for (int r = 0; r < 4; r++) {
            spart[r] += __shfl_xor(spart[r], o);
            dpart[r] += __shfl_xor(dpart[r], o);
        }
    }
    if (l15 == 0) {
#pragma unroll
        for (int r = 0; r < 4; r++) {
            sS[w][quad * 4 + r] = spart[r];
            sD[w][quad * 4 + r] = dpart[r];
        }
    }
    __syncthreads();
    if (t < 32) {
        int row = t & 15, hh2 = t >> 4;
        AS[(m0 + row) * 2 + hh2] = sS[2 * hh2][row] + sS[2 * hh2 + 1][row];
        AD[(m0 + row) * 2 + hh2] = sD[2 * hh2][row] + sD[2 * hh2 + 1][row];
    }
}

// ---------------------------------------------------------------------------
// Fused decoder GEMM + GAT GEMM + attention scores (layer boundary t=0 -> t=1).
// ---------------------------------------------------------------------------
__global__ __launch_bounds__(256) void gemm_decatt_kernel(
    const __hip_bfloat16* __restrict__ A, const __hip_bfloat16* __restrict__ WTdec,
    const __hip_bfloat16* __restrict__ WTgat, const void* __restrict__ b_dec,
    __hip_bfloat16* __restrict__ HH,
    const void* __restrict__ attS, const void* __restrict__ attD,
    float* __restrict__ AS, float* __restrict__ AD, const int* __restrict__ flags)
{
    const int f32 = flags[0];
    __shared__ __hip_bfloat16 zo[32][136];
    int w = threadIdx.x >> 6, l = threadIdx.x & 63;
    int rt = w >> 1, cg = w & 1;
    int l15 = l & 15, quad = l >> 4, kq = quad * 8;
    int m0 = blockIdx.x * 32;

    // -------- phase 1: decoder GEMM --------
    {
        int n0 = cg * 64;
        const __hip_bfloat16* arow = A + (size_t)(m0 + rt * 16 + l15) * 256 + kq;
        floatx4 acc[4];
#pragma unroll
        for (int ct = 0; ct < 4; ct++) acc[ct] = (floatx4){0.f, 0.f, 0.f, 0.f};
        for (int kc = 0; kc < 8; kc++) {
            short8 a = *(const short8*)(arow + kc * 32);
#pragma unroll
            for (int ct = 0; ct < 4; ct++) {
                const __hip_bfloat16* brow = WTdec + (size_t)(n0 + ct * 16 + l15) * 256 + kq;
                short8 b = *(const short8*)(brow + kc * 32);
                acc[ct] = __builtin_amdgcn_mfma_f32_16x16x32_bf16(a, b, acc[ct], 0, 0, 0);
            }
        }
#pragma unroll
        for (int ct = 0; ct < 4; ct++) {
            int col = n0 + ct * 16 + l15;
            float bb = ldf(b_dec, col, f32);
#pragma unroll
            for (int r = 0; r < 4; r++)
                zo[rt * 16 + quad * 4 + r][col] = __float2bfloat16(acc[ct][r] + bb);
        }
    }
    __syncthreads();

    // -------- phase 2: GAT GEMM + attention (32-row/CG=2 geometry) --------
    int n0 = cg * 128;
    floatx4 acc2[8];
#pragma unroll
    for (int ct = 0; ct < 8; ct++) acc2[ct] = (floatx4){0.f, 0.f, 0.f, 0.f};
    for (int kc = 0; kc < 4; kc++) {
        short8 a = *(const short8*)(&zo[rt * 16 + l15][kq + kc * 32]);
#pragma unroll
        for (int ct = 0; ct < 8; ct++) {
            const __hip_bfloat16* brow = WTgat + (size_t)(n0 + ct * 16 + l15) * 128 + kq;
            short8 b = *(const short8*)(brow + kc * 32);
            acc2[ct] = __builtin_amdgcn_mfma_f32_16x16x32_bf16(a, b, acc2[ct], 0, 0, 0);
        }
    }
    float spart[4] = {0.f, 0.f, 0.f, 0.f};
    float dpart[4] = {0.f, 0.f, 0.f, 0.f};
#pragma unroll
    for (int ct = 0; ct < 8; ct++) {
        int cm  = ct * 16 + l15;           // column within head [0,128)
        int col = n0 + cm;
        float as_w = ldf(attS, cg * CC + cm, f32);
        float ad_w = ldf(attD, cg * CC + cm, f32);
#pragma unroll
        for (int r = 0; r < 4; r++) {
            float v = acc2[ct][r];
            HH[(size_t)(m0 + rt * 16 + quad * 4 + r) * 256 + col] = __float2bfloat16(v);
            spart[r] += v * as_w;
            dpart[r] += v * ad_w;
        }
    }
#pragma unroll
    for (int o = 1; o <= 8; o <<= 1) {
#pragma unroll
        for (int r = 0; r < 4; r++) {
            spart[r] += __shfl_xor(spart[r], o);
            dpart[r] += __shfl_xor(dpart[r], o);
        }
    }
    if (l15 == 0) {
#pragma unroll
        for (int r = 0; r < 4; r++) {
            int row = m0 + rt * 16 + quad * 4 + r;
            AS[row * 2 + cg] = spart[r];
            AD[row * 2 + cg] = dpart[r];
        }
    }
}

// ---------------------------------------------------------------------------
// Fused GAT softmax + aggregation, single-stats-pass + 8-deep MLP agg loop.
// Bucket CSR (ushort): base = d<<7, len = deg[d]. ALPHA bf16 planes.
// ---------------------------------------------------------------------------
__global__ __launch_bounds__(256) void gat_fused_kernel(
    const uint2* __restrict__ HH2,
    const float* __restrict__ AS, const float* __restrict__ AD,
    const int* __restrict__ deg, const unsigned short* __restrict__ csr,
    const void* __restrict__ b_gat, __hip_bfloat16* __restrict__ ALPHA,
    uint2* __restrict__ OUT2, const int* __restrict__ flags)
{
    const int f32 = flags[0];
    int d = (blockIdx.x * blockDim.x + threadIdx.x) >> 6;
    int l = threadIdx.x & 63;
    if (d >= NN) return;
    int h = l >> 5, j = l & 31;
    int b = d << 7;
    int e = b + min(deg[d], CAP);
    float adh = AD[d * 2 + h];
    float self_e = expf(leaky02(AS[d * 2 + h] + adh));
    __hip_bfloat16* __restrict__ AH = ALPHA + (size_t)h * (NN * CAP);

    // single stats pass: exp(leaky logits) -> bf16 ALPHA plane + running sum
    float sum = (j == 0) ? self_e : 0.f;
    for (int i = b + j; i < e; i += 32) {
        float ex = expf(leaky02(AS[(int)csr[i] * 2 + h] + adh));
        __hip_bfloat16 exb = __float2bfloat16(ex);
        AH[i] = exb;
        sum += __bfloat162float(exb);
    }
#pragma unroll
    for (int o = 16; o; o >>= 1) sum += __shfl_xor(sum, o);   // within half
    float inv = 1.f / sum;

    // aggregation: lane l covers cols 4l..4l+3; accumulate unnormalized
    uint2 wv = HH2[(size_t)d * 64 + l];
    float4 p = bf4(wv.x, wv.y);
    float4 acc = make_float4(self_e * p.x, self_e * p.y, self_e * p.z, self_e * p.w);
    int i = b;
    for (; i + 8 <= e; i += 8) {
        int s0 = csr[i],     s1 = csr[i + 1], s2 = csr[i + 2], s3 = csr[i + 3];
        int s4 = csr[i + 4], s5 = csr[i + 5], s6 = csr[i + 6], s7 = csr[i + 7];
        float a1 = b2f(AH[i]),     a2 = b2f(AH[i + 1]), a3 = b2f(AH[i + 2]), a4 = b2f(AH[i + 3]);
        float a5 = b2f(AH[i + 4]), a6 = b2f(AH[i + 5]), a7 = b2f(AH[i + 6]), a8 = b2f(AH[i + 7]);
        uint2 w0 = HH2[(size_t)s0 * 64 + l];
        uint2 w1 = HH2[(size_t)s1 * 64 + l];
        uint2 w2 = HH2[(size_t)s2 * 64 + l];
        uint2 w3 = HH2[(size_t)s3 * 64 + l];
        uint2 w4 = HH2[(size_t)s4 * 64 + l];
        uint2 w5 = HH2[(size_t)s5 * 64 + l];
        uint2 w6 = HH2[(size_t)s6 * 64 + l];
        uint2 w7 = HH2[(size_t)s7 * 64 + l];
        float4 f;
        f = bf4(w0.x, w0.y); acc.x += a1 * f.x; acc.y += a1 * f.y; acc.z += a1 * f.z; acc.w += a1 * f.w;
        f = bf4(w1.x, w1.y); acc.x += a2 * f.x; acc.y += a2 * f.y; acc.z += a2 * f.z; acc.w += a2 * f.w;
        f = bf4(w2.x, w2.y); acc.x += a3 * f.x; acc.y += a3 * f.y; acc.z += a3 * f.z; acc.w += a3 * f.w;
        f = bf4(w3.x, w3.y); acc.x += a4 * f.x; acc.y += a4 * f.y; acc.z += a4 * f.z; acc.w += a4 * f.w;
        f = bf4(w4.x, w4.y); acc.x += a5 * f.x; acc.y += a5 * f.y; acc.z += a5 * f.z; acc.w += a5 * f.w;
        f = bf4(w5.x, w5.y); acc.x += a6 * f.x; acc.y += a6 * f.y; acc.z += a6 * f.z; acc.w += a6 * f.w;
        f = bf4(w6.x, w6.y); acc.x += a7 * f.x; acc.y += a7 * f.y; acc.z += a7 * f.z; acc.w += a7 * f.w;
        f = bf4(w7.x, w7.y); acc.x += a8 * f.x; acc.y += a8 * f.y; acc.z += a8 * f.z; acc.w += a8 * f.w;
    }
    for (; i + 4 <= e; i += 4) {
        int s0 = csr[i], s1 = csr[i + 1], s2 = csr[i + 2], s3 = csr[i + 3];
        float a1 = b2f(AH[i]), a2 = b2f(AH[i + 1]), a3 = b2f(AH[i + 2]), a4 = b2f(AH[i + 3]);
        uint2 w0 = HH2[(size_t)s0 * 64 + l];
        uint2 w1 = HH2[(size_t)s1 * 64 + l];
        uint2 w2 = HH2[(size_t)s2 * 64 + l];
        uint2 w3 = HH2[(size_t)s3 * 64 + l];
        float4 f;
        f = bf4(w0.x, w0.y); acc.x += a1 * f.x; acc.y += a1 * f.y; acc.z += a1 * f.z; acc.w += a1 * f.w;
        f = bf4(w1.x, w1.y); acc.x += a2 * f.x; acc.y += a2 * f.y; acc.z += a2 * f.z; acc.w += a2 * f.w;
        f = bf4(w2.x, w2.y); acc.x += a3 * f.x; acc.y += a3 * f.y; acc.z += a3 * f.z; acc.w += a3 * f.w;
        f = bf4(w3.x, w3.y); acc.x += a4 * f.x; acc.y += a4 * f.y; acc.z += a4 * f.z; acc.w += a4 * f.w;
    }
    for (; i < e; i++) {
        int s = csr[i];
        float al = b2f(AH[i]);
        uint2 wq = HH2[(size_t)s * 64 + l];
        float4 f = bf4(wq.x, wq.y);
        acc.x += al * f.x; acc.y += al * f.y; acc.z += al * f.z; acc.w += al * f.w;
    }
    int c0 = 4 * l;
    acc.x = acc.x * inv + ldf(b_gat, c0 + 0, f32);
    acc.y = acc.y * inv + ldf(b_gat, c0 + 1, f32);
    acc.z = acc.z * inv + ldf(b_gat, c0 + 2, f32);
    acc.w = acc.w * inv + ldf(b_gat, c0 + 3, f32);
    OUT2[(size_t)d * 64 + l] = f4bf(acc);
}

// ---------------------------------------------------------------------------
extern "C" void kernel_launch(void* const* d_in, const int* in_sizes, int n_in,
                              void* d_out, int out_size, void* d_ws, size_t ws_size,
                              hipStream_t stream)
{
    const void* xin    = d_in[0];
    const void* ei     = d_in[1];
    const void* eps    = d_in[2];
    const void* W_emb  = d_in[3];
    const void* b_emb  = d_in[4];
    const void* g_emb  = d_in[5];
    const void* be_emb = d_in[6];
    const void* W1     = d_in[7];
    const void* b1     = d_in[8];
    const void* g1     = d_in[9];
    const void* be1    = d_in[10];
    const void* W2     = d_in[11];
    const void* b2     = d_in[12];
    const void* W_mu   = d_in[13];
    const void* b_mu   = d_in[14];
    const void* W_var  = d_in[15];
    const void* b_var  = d_in[16];
    const void* W_gat  = d_in[17];
    const void* attS   = d_in[18];
    const void* attD   = d_in[19];
    const void* b_gat  = d_in[20];
    const void* W_dec  = d_in[21];
    const void* b_dec  = d_in[22];

    // workspace layout
    float* ws = (float*)d_ws;
    const size_t NB = (size_t)NN * CC;       // 2,560,000
    float* B0 = ws;                          // bf16 HH (N x 256)
    float* B1 = ws + 1 * NB;                 // bf16 Y | OUT (N x 256)
    float* B2 = ws + 2 * NB;                 // bf16 Xbf | Hbf
    __hip_bfloat16* Xbf   = (__hip_bfloat16*)B2;       // N x 128
    __hip_bfloat16* Hbf   = Xbf + NB;                  // N x 128 (W1 t=0 out)
    __hip_bfloat16* HHbf  = (__hip_bfloat16*)B0;       // N x 256
    __hip_bfloat16* OUTbf = (__hip_bfloat16*)B1;       // N x 256
    __hip_bfloat16* Ybf   = (__hip_bfloat16*)B1;       // N x 128 (pre-BN Y; W1 t=1 out)
    float* TAIL = ws + 4 * NB;
    float* AS      = TAIL;                        // 40000
    float* AD      = TAIL + 40000;                // 40000
    int*   FLAGS   = (int*)(TAIL + 80000);        // 16
    float* SUMSALL = (float*)(FLAGS + 16);        // 3 x 256
    int*   DEG     = (int*)(SUMSALL + 768);       // 20000 (zeroed by memset)
    float* PART    = (float*)(DEG + 20000);       // 1250*512 = 640000
    unsigned short* CSR16 = (unsigned short*)(PART + 640000);  // NN*CAP ushort
    __hip_bfloat16* ALPHAb = (__hip_bfloat16*)((float*)(PART + 640000) + NN * CAP / 2);
    __hip_bfloat16* WTB = (__hip_bfloat16*)((float*)(PART + 640000) + NN * CAP / 2 + NN * CAP);
    __hip_bfloat16* WTemb = WTB;
    __hip_bfloat16* WT1   = WTB + R0_;
    __hip_bfloat16* WT2   = WTB + R1_;
    __hip_bfloat16* WTmuv = WTB + R2_;       // mu|var contiguous -> NC=256
    __hip_bfloat16* WTgat = WTB + R4_;
    __hip_bfloat16* WTdec = WTB + R5_;
    __hip_bfloat16* Xin   = WTB + R6_;       // NN x 96 bf16

    const int GEMM_BLKS = NN / 32;           // 625

    // -------- memset: SUMSALL + DEG (contiguous; SUMSALL zero not strictly
    //          needed with plain-store reduce, kept for safety) --------
    hipMemsetAsync(SUMSALL, 0, (768 + 20000) * sizeof(int), stream);

    // -------- conversion ∥ region-partitioned bucket scatter (merged) --------
    cvt_scatter_kernel<<<HB + CVTB, 256, 0, stream>>>(
        W_emb, W1, W2, W_mu, W_var, W_gat, W_dec, xin,
        (const unsigned*)ei, WTB, FLAGS, DEG, CSR16);

    // -------- Stage A: Y = x @ W_emb + b_emb (+ BN-stats partials) ----------
    mfma_gemm_kernel<96, 128, 2, 1, 1, 0><<<GEMM_BLKS, 256, 0, stream>>>(
        Xin, WTemb, b_emb, Ybf, 0, PART, nullptr, nullptr, nullptr, FLAGS);
    bn_reduce_kernel<1><<<256, 256, 0, stream>>>(PART, SUMSALL, GEMM_BLKS);

    // -------- Stage B: GIN x2 (gather fused into W1; buffers ping-pong) -----
    // t=0: Ybf -(gather+BN_A+W1)-> Hbf; reduce; Hbf -(BN_A+W2)-> Xbf
    gemm_gin_kernel<1><<<NN / 16, 256, 0, stream>>>(
        (const uint2*)Ybf, WT1, b1, Hbf, PART, DEG, CSR16,
        SUMSALL, g_emb, be_emb, FLAGS);
    bn_reduce_kernel<0><<<256, 256, 0, stream>>>(PART, SUMSALL + 256, NN / 16);
    mfma_gemm_kernel<128, 128, 2, 1, 0, 1><<<GEMM_BLKS, 256, 0, stream>>>(
        Hbf, WT2, b2, Xbf, 0, nullptr, SUMSALL + 256, g1, be1, FLAGS);
    // t=1: Xbf -(gather+W1)-> Ybf; reduce; Ybf -(BN_A+W2)-> Xbf
    gemm_gin_kernel<0><<<NN / 16, 256, 0, stream>>>(
        (const uint2*)Xbf, WT1, b1, Ybf, PART, DEG, CSR16,
        nullptr, nullptr, nullptr, FLAGS);
    bn_reduce_kernel<0><<<256, 256, 0, stream>>>(PART, SUMSALL + 512, NN / 16);
    mfma_gemm_kernel<128, 128, 2, 1, 0, 1><<<GEMM_BLKS, 256, 0, stream>>>(
        Ybf, WT2, b2, Xbf, 0, nullptr, SUMSALL + 512, g1, be1, FLAGS);

    // -------- Stage C+D0: VAE heads + reparam + GAT GEMM t=0, fused ---------
    gemm_zatt_kernel<<<NN / 16, 256, 0, stream>>>(
        Xbf, WTmuv, WTgat, eps, b_mu, b_var, HHbf, attS, attD, AS, AD, d_out, FLAGS);
    gat_fused_kernel<<<(NN * 64) / 256, 256, 0, stream>>>(
        (const uint2*)HHbf, AS, AD, DEG, CSR16, b_gat, ALPHAb, (uint2*)OUTbf, FLAGS);

    // -------- dec t=0 + GAT GEMM t=1, fused ---------------------------------
    gemm_decatt_kernel<<<GEMM_BLKS, 256, 0, stream>>>(
        OUTbf, WTdec, WTgat, b_dec, HHbf, attS, attD, AS, AD, FLAGS);
    gat_fused_kernel<<<(NN * 64) / 256, 256, 0, stream>>>(
        (const uint2*)HHbf, AS, AD, DEG, CSR16, b_gat, ALPHAb, (uint2*)OUTbf, FLAGS);

    // -------- final decoder -> d_out (zout) ---------------------------------
    mfma_gemm_kernel<256, 128, 2, 2, 0, 0><<<GEMM_BLKS, 256, 0, stream>>>(
        OUTbf, WTdec, b_dec, d_out, NN * CC, nullptr, nullptr, nullptr, nullptr, FLAGS);
}